// Round 1
// baseline (267.765 us; speedup 1.0000x reference)
//
#include <hip/hip_runtime.h>
#include <math.h>

#define NTHREADS 256
#define NELEM    4096   // H*W = 64*64
#define VPT      4      // float4 loads per thread: 4*4*256 = 4096
#define NPART    8      // histogram replicas (contention spreading)
#define HSTRIDE  257    // 257 mod 32 == 1 -> replica p, bucket b hits bank (p+b)%32

// order-preserving float->uint map (ascending)
__device__ __forceinline__ unsigned f2ord(float f) {
    unsigned u = __float_as_uint(f);
    return (u & 0x80000000u) ? ~u : (u | 0x80000000u);
}
__device__ __forceinline__ float ord2f(unsigned k) {
    unsigned u = (k & 0x80000000u) ? (k ^ 0x80000000u) : ~k;
    return __uint_as_float(u);
}

// Histogram of next radix digit among keys matching (key & known) == pref.
__device__ __forceinline__ void histo_pass(const unsigned* keys, unsigned* hist,
                                           unsigned known, unsigned pref, int shift, int tid) {
    for (int i = tid; i < NPART * HSTRIDE; i += NTHREADS) hist[i] = 0u;
    __syncthreads();
    unsigned* myh = hist + (tid & (NPART - 1)) * HSTRIDE;
    const uint4* kp = (const uint4*)keys;
    #pragma unroll
    for (int j = 0; j < VPT; ++j) {
        uint4 kk = kp[j * NTHREADS + tid];
        unsigned karr[4] = {kk.x, kk.y, kk.z, kk.w};
        #pragma unroll
        for (int e = 0; e < 4; ++e) {
            unsigned k = karr[e];
            if ((k & known) == pref)
                atomicAdd(&myh[(k >> shift) & 0xFFu], 1u);
        }
    }
    __syncthreads();
}

// Reduce replicas, inclusive block scan, locate bucket(s) containing rank(s).
// Results broadcast via sh[0..3] = {bucketA, newRankA, bucketB, newRankB}.
__device__ __forceinline__ void scan_pick(const unsigned* hist, unsigned* scanbuf,
                                          int tid, unsigned rA, unsigned rB, bool doB,
                                          unsigned* sh) {
    unsigned cnt = 0;
    #pragma unroll
    for (int p = 0; p < NPART; ++p) cnt += hist[p * HSTRIDE + tid];
    scanbuf[tid] = cnt;
    __syncthreads();
    for (int off = 1; off < NTHREADS; off <<= 1) {
        unsigned add = (tid >= off) ? scanbuf[tid - off] : 0u;
        __syncthreads();
        scanbuf[tid] += add;
        __syncthreads();
    }
    unsigned inc = scanbuf[tid];
    unsigned exc = tid ? scanbuf[tid - 1] : 0u;
    if (rA >= exc && rA < inc) { sh[0] = (unsigned)tid; sh[1] = rA - exc; }
    if (doB && rB >= exc && rB < inc) { sh[2] = (unsigned)tid; sh[3] = rB - exc; }
    __syncthreads();
}

__global__ void __launch_bounds__(NTHREADS)
xsrelu_kernel(const float* __restrict__ x, const float* __restrict__ plogit,
              float* __restrict__ out, int C) {
    __shared__ __align__(16) unsigned keys[NELEM];        // 16 KiB
    __shared__ unsigned hist[NPART * HSTRIDE];            // ~8 KiB
    __shared__ unsigned scanbuf[NTHREADS];                // 1 KiB
    __shared__ unsigned sh[4];

    const int tid = threadIdx.x;
    const int row = blockIdx.x;
    const float4* xr = (const float4*)(x + (size_t)row * NELEM);

    // Load row once; keep values in registers, keys in LDS.
    float4 v[VPT];
    #pragma unroll
    for (int j = 0; j < VPT; ++j) {
        v[j] = xr[j * NTHREADS + tid];
        int base = (j * NTHREADS + tid) * 4;
        keys[base + 0] = f2ord(v[j].x);
        keys[base + 1] = f2ord(v[j].y);
        keys[base + 2] = f2ord(v[j].z);
        keys[base + 3] = f2ord(v[j].w);
    }

    // p0 drives the (scalar) rank indices; pc drives the interpolation.
    float p0 = 1.0f / (1.0f + expf(-plogit[0]));
    int c = row % C;
    float pc = 1.0f / (1.0f + expf(-plogit[c]));

    int kLow  = (int)((float)NELEM * (p0 - 0.02f));   // trunc toward zero, same as astype(int32)
    int kHigh = (int)((float)NELEM * (p0 + 0.02f));
    kLow  = min(max(kLow, 0),  NELEM - 1);
    kHigh = min(max(kHigh, 0), NELEM - 1);

    __syncthreads();  // keys visible

    // Dual MSB radix-256 select; share passes while prefixes agree.
    unsigned prefA = 0, prefB = 0, known = 0;
    unsigned rA = (unsigned)kLow, rB = (unsigned)kHigh;
    bool diverged = false;

    for (int shift = 24; shift >= 0; shift -= 8) {
        histo_pass(keys, hist, known, prefA, shift, tid);
        scan_pick(hist, scanbuf, tid, rA, rB, !diverged, sh);
        unsigned bA = sh[0], nrA = sh[1];
        if (!diverged) {
            unsigned bB = sh[2], nrB = sh[3];
            prefB = prefA | (bB << shift);
            prefA = prefA | (bA << shift);
            rA = nrA; rB = nrB;
            if (bA != bB) diverged = true;
        } else {
            prefA |= (bA << shift);
            rA = nrA;
            histo_pass(keys, hist, known, prefB, shift, tid);
            scan_pick(hist, scanbuf, tid, rB, rB, false, sh);
            prefB |= (sh[0] << shift);
            rB = sh[1];
        }
        known |= (0xFFu << shift);
    }

    float xlow  = ord2f(prefA);
    float xhigh = ord2f(prefB);
    float thr = xlow + (xhigh - xlow) * pc;

    float4* outr = (float4*)(out + (size_t)row * NELEM);
    #pragma unroll
    for (int j = 0; j < VPT; ++j) {
        float4 o;
        o.x = fmaxf(v[j].x - thr, 0.0f);
        o.y = fmaxf(v[j].y - thr, 0.0f);
        o.z = fmaxf(v[j].z - thr, 0.0f);
        o.w = fmaxf(v[j].w - thr, 0.0f);
        outr[j * NTHREADS + tid] = o;
    }
}

extern "C" void kernel_launch(void* const* d_in, const int* in_sizes, int n_in,
                              void* d_out, int out_size, void* d_ws, size_t ws_size,
                              hipStream_t stream) {
    const float* x      = (const float*)d_in[0];
    const float* plogit = (const float*)d_in[1];
    float* out          = (float*)d_out;
    int C    = in_sizes[1];              // 256
    int rows = in_sizes[0] / NELEM;      // 8192
    xsrelu_kernel<<<rows, NTHREADS, 0, stream>>>(x, plogit, out, C);
}